// Round 8
// baseline (1675.497 us; speedup 1.0000x reference)
//
#include <hip/hip_runtime.h>

#define NNODES 50000
#define NEDGES 1600000
#define NB2 782       // buckets of 64 nodes: bucket = dst>>6
#define BCAP2 2816    // edges per bucket cap (mean 2048, +17 sigma)
#define QS 136        // Q LDS stage row stride (ushorts) — bank-spread, 16B-aligned
#define AS 132        // acc LDS row stride (floats) — bank-spread, 16B-aligned

typedef __attribute__((ext_vector_type(8))) short short8;   // 8 x bf16
typedef __attribute__((ext_vector_type(4))) float fp32x4;   // MFMA C/D frag

__device__ __forceinline__ unsigned short f2bf(float f) {   // RNE fp32 -> bf16
    unsigned int u = __float_as_uint(f);
    u += 0x7fffu + ((u >> 16) & 1u);
    return (unsigned short)(u >> 16);
}
__device__ __forceinline__ float bflo(unsigned int p) { return __uint_as_float(p << 16); }
__device__ __forceinline__ float bfhi(unsigned int p) { return __uint_as_float(p & 0xffff0000u); }

// 16-term bf16 dot: (ka,kc) . (qa,qc), fp32 accumulate
__device__ __forceinline__ float dot16(uint4 ka, uint4 kc, uint4 qa, uint4 qc)
{
    float p;
    p = fmaf(bfhi(ka.x), bfhi(qa.x), bflo(ka.x) * bflo(qa.x));
    p = fmaf(bflo(ka.y), bflo(qa.y), p); p = fmaf(bfhi(ka.y), bfhi(qa.y), p);
    p = fmaf(bflo(ka.z), bflo(qa.z), p); p = fmaf(bfhi(ka.z), bfhi(qa.z), p);
    p = fmaf(bflo(ka.w), bflo(qa.w), p); p = fmaf(bfhi(ka.w), bfhi(qa.w), p);
    p = fmaf(bflo(kc.x), bflo(qc.x), p); p = fmaf(bfhi(kc.x), bfhi(qc.x), p);
    p = fmaf(bflo(kc.y), bflo(qc.y), p); p = fmaf(bfhi(kc.y), bfhi(qc.y), p);
    p = fmaf(bflo(kc.z), bflo(qc.z), p); p = fmaf(bfhi(kc.z), bfhi(qc.z), p);
    p = fmaf(bflo(kc.w), bflo(qc.w), p); p = fmaf(bfhi(kc.w), bfhi(qc.w), p);
    return p;
}

// ---------------------------------------------------------------------------
// Cast + transpose W (128x128 fp32, k-major) -> WT bf16 (n-major).
// Blocks 0..7 also zero gcur[1024] (replaces a memset dispatch).
// ---------------------------------------------------------------------------
__global__ __launch_bounds__(128) void cast_wt(
    const float* __restrict__ WQ, const float* __restrict__ WK,
    const float* __restrict__ WV, unsigned short* __restrict__ WT,
    int* __restrict__ gcur)
{
    if (blockIdx.x < 8) gcur[blockIdx.x * 128 + threadIdx.x] = 0;
    const int w = blockIdx.x >> 7;
    const int n = blockIdx.x & 127;
    const int k = threadIdx.x;
    const float* W = (w == 0) ? WQ : ((w == 1) ? WK : WV);
    WT[w * 16384 + n * 128 + k] = f2bf(W[k * 128 + n]);
}

// ---------------------------------------------------------------------------
// Fused QKV projection, bf16 MFMA 16x16x32, fp32 state read + in-register
// cast. Outputs: Qb [n][128] bf16, KVb [n][256] bf16 (K cols 0..127, V cols
// 128..255). Epilogue: bias add + LDS transpose -> coalesced bf16x8 stores.
// ---------------------------------------------------------------------------
__global__ __launch_bounds__(256) void proj_mfma(
    const float* __restrict__ state, const unsigned short* __restrict__ WT,
    const float* __restrict__ bQ, const float* __restrict__ bK,
    const float* __restrict__ bV,
    unsigned short* __restrict__ Qb, unsigned short* __restrict__ KVb)
{
    __shared__ float lbuf[4][16 * 132];

    const int tid  = threadIdx.x;
    const int wv   = tid >> 6;
    const int lane = tid & 63;
    const int lm   = lane & 15;
    const int quad = lane >> 4;
    const int m0   = blockIdx.x * 64 + wv * 16;
    const int m    = m0 + lm;

    fp32x4 acc[3][8];
#pragma unroll
    for (int w = 0; w < 3; ++w)
#pragma unroll
        for (int t = 0; t < 8; ++t)
            acc[w][t] = (fp32x4){0.f, 0.f, 0.f, 0.f};

    const int kq = quad * 8;
#pragma unroll
    for (int kb = 0; kb < 128; kb += 32) {
        short8 a = (short8){0,0,0,0,0,0,0,0};
        if (m < NNODES) {
            const float4 f0 = *(const float4*)(state + (size_t)m * 128 + kb + kq);
            const float4 f1 = *(const float4*)(state + (size_t)m * 128 + kb + kq + 4);
            a[0] = (short)f2bf(f0.x); a[1] = (short)f2bf(f0.y);
            a[2] = (short)f2bf(f0.z); a[3] = (short)f2bf(f0.w);
            a[4] = (short)f2bf(f1.x); a[5] = (short)f2bf(f1.y);
            a[6] = (short)f2bf(f1.z); a[7] = (short)f2bf(f1.w);
        }
#pragma unroll
        for (int w = 0; w < 3; ++w) {
#pragma unroll
            for (int t = 0; t < 8; ++t) {
                const short8 b = *(const short8*)(WT + w * 16384 + (t * 16 + lm) * 128 + kb + kq);
                acc[w][t] = __builtin_amdgcn_mfma_f32_16x16x32_bf16(a, b, acc[w][t], 0, 0, 0);
            }
        }
    }

    const int rrow = lane >> 2;
    const int rcol = (lane & 3) * 32;
    const int grow = m0 + rrow;
#pragma unroll
    for (int w = 0; w < 3; ++w) {
        const float* bp = (w == 0) ? bQ : ((w == 1) ? bK : bV);
        float* L = &lbuf[wv][0];
#pragma unroll
        for (int t = 0; t < 8; ++t) {
            const float bb = bp[t * 16 + lm];
#pragma unroll
            for (int r = 0; r < 4; ++r)
                L[(quad * 4 + r) * 132 + t * 16 + lm] = acc[w][t][r] + bb;
        }
        __syncthreads();
        if (grow < NNODES) {
            unsigned short* gp;
            if (w == 0)      gp = Qb  + (size_t)grow * 128 + rcol;
            else if (w == 1) gp = KVb + (size_t)grow * 256 + rcol;
            else             gp = KVb + (size_t)grow * 256 + 128 + rcol;
#pragma unroll
            for (int c = 0; c < 4; ++c) {
                const float* lp = &L[rrow * 132 + rcol + c * 8];
                const float4 x0 = *(const float4*)(lp);
                const float4 x1 = *(const float4*)(lp + 4);
                short8 r;
                r[0] = (short)f2bf(x0.x); r[1] = (short)f2bf(x0.y);
                r[2] = (short)f2bf(x0.z); r[3] = (short)f2bf(x0.w);
                r[4] = (short)f2bf(x1.x); r[5] = (short)f2bf(x1.y);
                r[6] = (short)f2bf(x1.z); r[7] = (short)f2bf(x1.w);
                *(short8*)(gp + c * 8) = r;
            }
        }
        __syncthreads();
    }
}

// ---------------------------------------------------------------------------
// Pass 1: bin edges by dst>>6 into 782 buckets. 2048 edges/block. LDS hist
// over 1024 padded bins (thread owns 4 consecutive), two-level scan, <=~725
// global atomics/block, in-LDS grouping, bucket-grouped SoA writes.
// ---------------------------------------------------------------------------
__global__ __launch_bounds__(256) void bucket_pass1(
    const int* __restrict__ src, const int* __restrict__ dst,
    int* __restrict__ gcur, int* __restrict__ dbuf, int* __restrict__ sbuf)
{
    __shared__ int hist[1024];
    __shared__ int lofs[1024];
    __shared__ int gbase[1024];
    __shared__ int psum[256];
    __shared__ int stot;
    __shared__ int dstg[2048];
    __shared__ int srcg[2048];

    const int t = threadIdx.x;
#pragma unroll
    for (int j = 0; j < 4; ++j) hist[t + 256 * j] = 0;
    __syncthreads();

    const long long e0 = (long long)blockIdx.x * 2048 + t * 8;
    const bool valid = (e0 < NEDGES);
    int4 sA, sB, dA, dB;
    int b[8], r[8];
    if (valid) {
        sA = *(const int4*)(src + e0);  sB = *(const int4*)(src + e0 + 4);
        dA = *(const int4*)(dst + e0);  dB = *(const int4*)(dst + e0 + 4);
        const int dd[8] = {dA.x, dA.y, dA.z, dA.w, dB.x, dB.y, dB.z, dB.w};
#pragma unroll
        for (int j = 0; j < 8; ++j) {
            b[j] = dd[j] >> 6;
            r[j] = atomicAdd(&hist[b[j]], 1);
        }
    }
    __syncthreads();

    // two-level exclusive scan: thread t owns bins 4t..4t+3 (natural order)
    const int h0 = hist[4 * t], h1 = hist[4 * t + 1],
              h2 = hist[4 * t + 2], h3 = hist[4 * t + 3];
    psum[t] = h0 + h1 + h2 + h3;
    __syncthreads();
    for (int off = 1; off < 256; off <<= 1) {
        const int y = (t >= off) ? psum[t - off] : 0;
        __syncthreads();
        psum[t] += y;
        __syncthreads();
    }
    if (t == 255) stot = psum[255];
    int run = (t == 0) ? 0 : psum[t - 1];
    lofs[4 * t] = run; run += h0;
    lofs[4 * t + 1] = run; run += h1;
    lofs[4 * t + 2] = run; run += h2;
    lofs[4 * t + 3] = run;
    if (h0 > 0) gbase[4 * t]     = atomicAdd(&gcur[4 * t],     h0);
    if (h1 > 0) gbase[4 * t + 1] = atomicAdd(&gcur[4 * t + 1], h1);
    if (h2 > 0) gbase[4 * t + 2] = atomicAdd(&gcur[4 * t + 2], h2);
    if (h3 > 0) gbase[4 * t + 3] = atomicAdd(&gcur[4 * t + 3], h3);
    __syncthreads();

    if (valid) {
        const int dd[8] = {dA.x, dA.y, dA.z, dA.w, dB.x, dB.y, dB.z, dB.w};
        const int ss[8] = {sA.x, sA.y, sA.z, sA.w, sB.x, sB.y, sB.z, sB.w};
#pragma unroll
        for (int j = 0; j < 8; ++j) {
            const int p = lofs[b[j]] + r[j];
            dstg[p] = dd[j];
            srcg[p] = ss[j];
        }
    }
    __syncthreads();

    const int tot = stot;
#pragma unroll
    for (int j = 0; j < 8; ++j) {
        const int slot = t + 256 * j;
        if (slot < tot) {
            const int dd = dstg[slot];
            const int bb = dd >> 6;
            const int loc = gbase[bb] + (slot - lofs[bb]);
            if (loc < BCAP2) {
                const int g = bb * BCAP2 + loc;
                dbuf[g] = dd;
                sbuf[g] = srcg[slot];
            }
        }
    }
}

// ---------------------------------------------------------------------------
// Fused aggregation: one 256-thread block per 64-node bucket (~2048 edges,
// balanced +-2%). Bucket Q rows staged in LDS; lane=(edge eo=t>>3, head
// h=t&7) computes full 16-dim dot from 2 global dwordx4 K loads + 2 LDS Q
// reads, exp, then ds_add_f32 of w*V into a 64x132 fp32 LDS tile + z.
// No CSR, no eidx, no per-node grouping. Epilogue: normalize, float4 stores.
// ---------------------------------------------------------------------------
__global__ __launch_bounds__(256) void bucket_agg(
    const int* __restrict__ dbuf, const int* __restrict__ sbuf,
    const int* __restrict__ gcur,
    const unsigned short* __restrict__ Qb, const unsigned short* __restrict__ KVb,
    float* __restrict__ out)
{
    __shared__ float accL[64 * AS];            // 33.8 KB
    __shared__ float zL[64 * 8];               // 2 KB
    __shared__ unsigned short Qs[64 * QS];     // 17.4 KB

    const int b  = blockIdx.x;
    const int t  = threadIdx.x;
    const int n0 = b * 64;
    const int h  = t & 7;
    const int eo = t >> 3;     // 0..31

    for (int i = t; i < 64 * AS; i += 256) accL[i] = 0.f;
    // FIX (round 7 bug): zL has 512 entries but only 256 threads — the old
    // `if (t < 512) zL[t]=0` left rows 32..63 holding stale LDS from prior
    // kernels on this CU -> wrong normalization for half of every bucket.
    for (int i = t; i < 64 * 8; i += 256) zL[i] = 0.f;

    const int nvalid = (NNODES - n0 < 64) ? (NNODES - n0) : 64;
    for (int i = t; i < nvalid * 16; i += 256) {
        const int row = i >> 4, c = i & 15;
        const uint4 qv = *(const uint4*)(Qb + (size_t)(n0 + row) * 128 + c * 8);
        *(uint4*)(&Qs[row * QS + c * 8]) = qv;
    }
    __syncthreads();

    int cnt = gcur[b];
    if (cnt > BCAP2) cnt = BCAP2;
    const int base = b * BCAP2;

    for (int i0 = 0; i0 < cnt; i0 += 64) {
        const int iA = i0 + eo;
        const int iB = iA + 32;
        const bool a0 = (iA < cnt);
        const bool a1 = (iB < cnt);
        const int ia = a0 ? iA : 0;
        const int ib = a1 ? iB : 0;

        const int d0 = dbuf[base + ia], s0 = sbuf[base + ia];
        const int d1 = dbuf[base + ib], s1 = sbuf[base + ib];

        const unsigned short* kp0 = KVb + (size_t)s0 * 256 + h * 16;
        const unsigned short* kp1 = KVb + (size_t)s1 * 256 + h * 16;
        const uint4 ka0 = *(const uint4*)(kp0);
        const uint4 kc0 = *(const uint4*)(kp0 + 8);
        const uint4 va0 = *(const uint4*)(kp0 + 128);
        const uint4 vc0 = *(const uint4*)(kp0 + 136);
        const uint4 ka1 = *(const uint4*)(kp1);
        const uint4 kc1 = *(const uint4*)(kp1 + 8);
        const uint4 va1 = *(const uint4*)(kp1 + 128);
        const uint4 vc1 = *(const uint4*)(kp1 + 136);

        const int l0 = (d0 & 63), l1 = (d1 & 63);
        const int q0o = l0 * QS + h * 16;
        const int q1o = l1 * QS + h * 16;
        const uint4 qa0 = *(const uint4*)(&Qs[q0o]);
        const uint4 qc0 = *(const uint4*)(&Qs[q0o + 8]);
        const uint4 qa1 = *(const uint4*)(&Qs[q1o]);
        const uint4 qc1 = *(const uint4*)(&Qs[q1o + 8]);

        const float p0 = dot16(ka0, kc0, qa0, qc0);
        const float p1 = dot16(ka1, kc1, qa1, qc1);

        float w0 = __expf(fminf(fmaxf(p0 * 0.25f, -5.f), 5.f));
        float w1 = __expf(fminf(fmaxf(p1 * 0.25f, -5.f), 5.f));
        w0 = a0 ? w0 : 0.f;     // masked lanes add exact 0.0 — harmless
        w1 = a1 ? w1 : 0.f;

        atomicAdd(&zL[l0 * 8 + h], w0);
        atomicAdd(&zL[l1 * 8 + h], w1);

        float* A0 = &accL[l0 * AS + h * 16];
        float* A1 = &accL[l1 * AS + h * 16];
        atomicAdd(A0 + 0,  bflo(va0.x) * w0); atomicAdd(A0 + 1,  bfhi(va0.x) * w0);
        atomicAdd(A0 + 2,  bflo(va0.y) * w0); atomicAdd(A0 + 3,  bfhi(va0.y) * w0);
        atomicAdd(A0 + 4,  bflo(va0.z) * w0); atomicAdd(A0 + 5,  bfhi(va0.z) * w0);
        atomicAdd(A0 + 6,  bflo(va0.w) * w0); atomicAdd(A0 + 7,  bfhi(va0.w) * w0);
        atomicAdd(A0 + 8,  bflo(vc0.x) * w0); atomicAdd(A0 + 9,  bfhi(vc0.x) * w0);
        atomicAdd(A0 + 10, bflo(vc0.y) * w0); atomicAdd(A0 + 11, bfhi(vc0.y) * w0);
        atomicAdd(A0 + 12, bflo(vc0.z) * w0); atomicAdd(A0 + 13, bfhi(vc0.z) * w0);
        atomicAdd(A0 + 14, bflo(vc0.w) * w0); atomicAdd(A0 + 15, bfhi(vc0.w) * w0);

        atomicAdd(A1 + 0,  bflo(va1.x) * w1); atomicAdd(A1 + 1,  bfhi(va1.x) * w1);
        atomicAdd(A1 + 2,  bflo(va1.y) * w1); atomicAdd(A1 + 3,  bfhi(va1.y) * w1);
        atomicAdd(A1 + 4,  bflo(va1.z) * w1); atomicAdd(A1 + 5,  bfhi(va1.z) * w1);
        atomicAdd(A1 + 6,  bflo(va1.w) * w1); atomicAdd(A1 + 7,  bfhi(va1.w) * w1);
        atomicAdd(A1 + 8,  bflo(vc1.x) * w1); atomicAdd(A1 + 9,  bfhi(vc1.x) * w1);
        atomicAdd(A1 + 10, bflo(vc1.y) * w1); atomicAdd(A1 + 11, bfhi(vc1.y) * w1);
        atomicAdd(A1 + 12, bflo(vc1.z) * w1); atomicAdd(A1 + 13, bfhi(vc1.z) * w1);
        atomicAdd(A1 + 14, bflo(vc1.w) * w1); atomicAdd(A1 + 15, bfhi(vc1.w) * w1);
    }
    __syncthreads();

    // normalize + write: nvalid rows x 32 float4s
    for (int i = t; i < nvalid * 32; i += 256) {
        const int row = i >> 5, c4 = i & 31;
        const float inv = 1.0f / zL[row * 8 + (c4 >> 2)];
        const float4 a = *(const float4*)(&accL[row * AS + c4 * 4]);
        float4 rr;
        rr.x = a.x * inv; rr.y = a.y * inv; rr.z = a.z * inv; rr.w = a.w * inv;
        *(float4*)(out + (size_t)(n0 + row) * 128 + c4 * 4) = rr;
    }
}

extern "C" void kernel_launch(void* const* d_in, const int* in_sizes, int n_in,
                              void* d_out, int out_size, void* d_ws, size_t ws_size,
                              hipStream_t stream)
{
    const float* state = (const float*)d_in[0];
    const int*   src   = (const int*)d_in[1];
    const int*   dst   = (const int*)d_in[2];
    const float* WQ    = (const float*)d_in[3];
    const float* bQ    = (const float*)d_in[4];
    const float* WK    = (const float*)d_in[5];
    const float* bK    = (const float*)d_in[6];
    const float* WV    = (const float*)d_in[7];
    const float* bV    = (const float*)d_in[8];
    float* out = (float*)d_out;

    unsigned short* Qb  = (unsigned short*)d_ws;                 // 12.8 MB
    unsigned short* KVb = Qb + (size_t)NNODES * 128;             // 25.6 MB
    unsigned short* WT  = KVb + (size_t)NNODES * 256;            // 96 KB
    int* dbuf = (int*)(WT + 3 * 16384);                          // NB2*BCAP2*4B = 8.8 MB
    int* sbuf = dbuf + (size_t)NB2 * BCAP2;                      // 8.8 MB
    int* gcur = sbuf + (size_t)NB2 * BCAP2;                      // 1024 ints

    cast_wt<<<3 * 128, 128, 0, stream>>>(WQ, WK, WV, WT, gcur);
    proj_mfma<<<(NNODES + 63) / 64, 256, 0, stream>>>(state, WT, bQ, bK, bV, Qb, KVb);

    bucket_pass1<<<(NEDGES + 2047) / 2048, 256, 0, stream>>>(src, dst, gcur, dbuf, sbuf);
    bucket_agg<<<NB2, 256, 0, stream>>>(dbuf, sbuf, gcur, Qb, KVb, out);
}

// Round 9
// 336.667 us; speedup vs baseline: 4.9767x; 4.9767x over previous
//
#include <hip/hip_runtime.h>

#define NNODES 50000
#define NEDGES 1600000
#define NB2 782       // buckets of 64 nodes: bucket = dst>>6
#define BCAP2 2816    // edges per bucket cap (mean 2048, +17 sigma)

typedef __attribute__((ext_vector_type(8))) short short8;   // 8 x bf16
typedef __attribute__((ext_vector_type(4))) float fp32x4;   // MFMA C/D frag

__device__ __forceinline__ unsigned short f2bf(float f) {   // RNE fp32 -> bf16
    unsigned int u = __float_as_uint(f);
    u += 0x7fffu + ((u >> 16) & 1u);
    return (unsigned short)(u >> 16);
}
__device__ __forceinline__ float bflo(unsigned int p) { return __uint_as_float(p << 16); }
__device__ __forceinline__ float bfhi(unsigned int p) { return __uint_as_float(p & 0xffff0000u); }

// ---------------------------------------------------------------------------
// Cast + transpose W (128x128 fp32, k-major) -> WT bf16 (n-major).
// Blocks 0..7 also zero gcur[1024] (replaces a memset dispatch).
// ---------------------------------------------------------------------------
__global__ __launch_bounds__(128) void cast_wt(
    const float* __restrict__ WQ, const float* __restrict__ WK,
    const float* __restrict__ WV, unsigned short* __restrict__ WT,
    int* __restrict__ gcur)
{
    if (blockIdx.x < 8) gcur[blockIdx.x * 128 + threadIdx.x] = 0;
    const int w = blockIdx.x >> 7;
    const int n = blockIdx.x & 127;
    const int k = threadIdx.x;
    const float* W = (w == 0) ? WQ : ((w == 1) ? WK : WV);
    WT[w * 16384 + n * 128 + k] = f2bf(W[k * 128 + n]);
}

// ---------------------------------------------------------------------------
// Fused QKV projection, bf16 MFMA 16x16x32, fp32 state read + in-register
// cast. Outputs: Qb [n][128] bf16, KVb [n][256] bf16 (K cols 0..127, V cols
// 128..255). Epilogue: bias add + LDS transpose -> coalesced bf16x8 stores.
// ---------------------------------------------------------------------------
__global__ __launch_bounds__(256) void proj_mfma(
    const float* __restrict__ state, const unsigned short* __restrict__ WT,
    const float* __restrict__ bQ, const float* __restrict__ bK,
    const float* __restrict__ bV,
    unsigned short* __restrict__ Qb, unsigned short* __restrict__ KVb)
{
    __shared__ float lbuf[4][16 * 132];

    const int tid  = threadIdx.x;
    const int wv   = tid >> 6;
    const int lane = tid & 63;
    const int lm   = lane & 15;
    const int quad = lane >> 4;
    const int m0   = blockIdx.x * 64 + wv * 16;
    const int m    = m0 + lm;

    fp32x4 acc[3][8];
#pragma unroll
    for (int w = 0; w < 3; ++w)
#pragma unroll
        for (int t = 0; t < 8; ++t)
            acc[w][t] = (fp32x4){0.f, 0.f, 0.f, 0.f};

    const int kq = quad * 8;
#pragma unroll
    for (int kb = 0; kb < 128; kb += 32) {
        short8 a = (short8){0,0,0,0,0,0,0,0};
        if (m < NNODES) {
            const float4 f0 = *(const float4*)(state + (size_t)m * 128 + kb + kq);
            const float4 f1 = *(const float4*)(state + (size_t)m * 128 + kb + kq + 4);
            a[0] = (short)f2bf(f0.x); a[1] = (short)f2bf(f0.y);
            a[2] = (short)f2bf(f0.z); a[3] = (short)f2bf(f0.w);
            a[4] = (short)f2bf(f1.x); a[5] = (short)f2bf(f1.y);
            a[6] = (short)f2bf(f1.z); a[7] = (short)f2bf(f1.w);
        }
#pragma unroll
        for (int w = 0; w < 3; ++w) {
#pragma unroll
            for (int t = 0; t < 8; ++t) {
                const short8 b = *(const short8*)(WT + w * 16384 + (t * 16 + lm) * 128 + kb + kq);
                acc[w][t] = __builtin_amdgcn_mfma_f32_16x16x32_bf16(a, b, acc[w][t], 0, 0, 0);
            }
        }
    }

    const int rrow = lane >> 2;
    const int rcol = (lane & 3) * 32;
    const int grow = m0 + rrow;
#pragma unroll
    for (int w = 0; w < 3; ++w) {
        const float* bp = (w == 0) ? bQ : ((w == 1) ? bK : bV);
        float* L = &lbuf[wv][0];
#pragma unroll
        for (int t = 0; t < 8; ++t) {
            const float bb = bp[t * 16 + lm];
#pragma unroll
            for (int r = 0; r < 4; ++r)
                L[(quad * 4 + r) * 132 + t * 16 + lm] = acc[w][t][r] + bb;
        }
        __syncthreads();
        if (grow < NNODES) {
            unsigned short* gp;
            if (w == 0)      gp = Qb  + (size_t)grow * 128 + rcol;
            else if (w == 1) gp = KVb + (size_t)grow * 256 + rcol;
            else             gp = KVb + (size_t)grow * 256 + 128 + rcol;
#pragma unroll
            for (int c = 0; c < 4; ++c) {
                const float* lp = &L[rrow * 132 + rcol + c * 8];
                const float4 x0 = *(const float4*)(lp);
                const float4 x1 = *(const float4*)(lp + 4);
                short8 r;
                r[0] = (short)f2bf(x0.x); r[1] = (short)f2bf(x0.y);
                r[2] = (short)f2bf(x0.z); r[3] = (short)f2bf(x0.w);
                r[4] = (short)f2bf(x1.x); r[5] = (short)f2bf(x1.y);
                r[6] = (short)f2bf(x1.z); r[7] = (short)f2bf(x1.w);
                *(short8*)(gp + c * 8) = r;
            }
        }
        __syncthreads();
    }
}

// ---------------------------------------------------------------------------
// Pass 1: bin edges by dst>>6 into 782 buckets. 2048 edges/block. LDS hist
// over 1024 padded bins, two-level scan, in-LDS grouping, bucket-grouped
// SoA writes of (dst,src). (Proven correct in round 8.)
// ---------------------------------------------------------------------------
__global__ __launch_bounds__(256) void bucket_pass1(
    const int* __restrict__ src, const int* __restrict__ dst,
    int* __restrict__ gcur, int* __restrict__ dbuf, int* __restrict__ sbuf)
{
    __shared__ int hist[1024];
    __shared__ int lofs[1024];
    __shared__ int gbase[1024];
    __shared__ int psum[256];
    __shared__ int stot;
    __shared__ int dstg[2048];
    __shared__ int srcg[2048];

    const int t = threadIdx.x;
#pragma unroll
    for (int j = 0; j < 4; ++j) hist[t + 256 * j] = 0;
    __syncthreads();

    const long long e0 = (long long)blockIdx.x * 2048 + t * 8;
    const bool valid = (e0 < NEDGES);
    int4 sA, sB, dA, dB;
    int b[8], r[8];
    if (valid) {
        sA = *(const int4*)(src + e0);  sB = *(const int4*)(src + e0 + 4);
        dA = *(const int4*)(dst + e0);  dB = *(const int4*)(dst + e0 + 4);
        const int dd[8] = {dA.x, dA.y, dA.z, dA.w, dB.x, dB.y, dB.z, dB.w};
#pragma unroll
        for (int j = 0; j < 8; ++j) {
            b[j] = dd[j] >> 6;
            r[j] = atomicAdd(&hist[b[j]], 1);
        }
    }
    __syncthreads();

    // two-level exclusive scan: thread t owns bins 4t..4t+3
    const int h0 = hist[4 * t], h1 = hist[4 * t + 1],
              h2 = hist[4 * t + 2], h3 = hist[4 * t + 3];
    psum[t] = h0 + h1 + h2 + h3;
    __syncthreads();
    for (int off = 1; off < 256; off <<= 1) {
        const int y = (t >= off) ? psum[t - off] : 0;
        __syncthreads();
        psum[t] += y;
        __syncthreads();
    }
    if (t == 255) stot = psum[255];
    int run = (t == 0) ? 0 : psum[t - 1];
    lofs[4 * t] = run; run += h0;
    lofs[4 * t + 1] = run; run += h1;
    lofs[4 * t + 2] = run; run += h2;
    lofs[4 * t + 3] = run;
    if (h0 > 0) gbase[4 * t]     = atomicAdd(&gcur[4 * t],     h0);
    if (h1 > 0) gbase[4 * t + 1] = atomicAdd(&gcur[4 * t + 1], h1);
    if (h2 > 0) gbase[4 * t + 2] = atomicAdd(&gcur[4 * t + 2], h2);
    if (h3 > 0) gbase[4 * t + 3] = atomicAdd(&gcur[4 * t + 3], h3);
    __syncthreads();

    if (valid) {
        const int dd[8] = {dA.x, dA.y, dA.z, dA.w, dB.x, dB.y, dB.z, dB.w};
        const int ss[8] = {sA.x, sA.y, sA.z, sA.w, sB.x, sB.y, sB.z, sB.w};
#pragma unroll
        for (int j = 0; j < 8; ++j) {
            const int p = lofs[b[j]] + r[j];
            dstg[p] = dd[j];
            srcg[p] = ss[j];
        }
    }
    __syncthreads();

    const int tot = stot;
#pragma unroll
    for (int j = 0; j < 8; ++j) {
        const int slot = t + 256 * j;
        if (slot < tot) {
            const int dd = dstg[slot];
            const int bb = dd >> 6;
            const int loc = gbase[bb] + (slot - lofs[bb]);
            if (loc < BCAP2) {
                const int g = bb * BCAP2 + loc;
                dbuf[g] = dd;
                sbuf[g] = srcg[slot];
            }
        }
    }
}

// ---------------------------------------------------------------------------
// Pass 2: one block per 64-node bucket (782 blocks — 4x the round-6
// parallelism). 64-bin LDS hist, single-wave shfl_up scan (no barrier
// ladder), in-LDS grouping of src ids, coalesced eidx write + offs2.
// ---------------------------------------------------------------------------
__global__ __launch_bounds__(256) void bucket_pass2(
    const int* __restrict__ dbuf, const int* __restrict__ sbuf,
    const int* __restrict__ gcur, int* __restrict__ eidx, int2* __restrict__ offs2)
{
    __shared__ int hist[64];
    __shared__ int cur[64];
    __shared__ int srcbuf[BCAP2];   // 11 KB

    const int b = blockIdx.x;
    const int t = threadIdx.x;
    int cnt = gcur[b];
    if (cnt > BCAP2) cnt = BCAP2;
    const int base = b * BCAP2;

    if (t < 64) hist[t] = 0;
    __syncthreads();

    for (int i = t; i < cnt; i += 256)
        atomicAdd(&hist[dbuf[base + i] & 63], 1);
    __syncthreads();

    if (t < 64) {                       // threads 0..63 = one full wave
        const int v = hist[t];
        int s = v;                      // inclusive scan via shfl_up
#pragma unroll
        for (int off = 1; off < 64; off <<= 1) {
            const int y = __shfl_up(s, off);
            if (t >= off) s += y;
        }
        cur[t] = s - v;                 // exclusive prefix
        const int n = b * 64 + t;
        if (n < NNODES) {
            int2 oe; oe.x = base + s - v; oe.y = base + s;
            offs2[n] = oe;
        }
    }
    __syncthreads();

    for (int i = t; i < cnt; i += 256) {
        const int p = atomicAdd(&cur[dbuf[base + i] & 63], 1);
        srcbuf[p] = sbuf[base + i];
    }
    __syncthreads();

    for (int i = t; i < cnt; i += 256)
        eidx[base + i] = srcbuf[i];
}

// ---------------------------------------------------------------------------
// Aggregation (round-6 proven version, 102.8 us): one wave per dst node;
// lane = (edge-slot eo=l>>3, head h=l&7); 16 edges/iteration of independent
// dwordx4 gathers; register accumulation; one cross-lane reduce per node.
// ---------------------------------------------------------------------------
__global__ __launch_bounds__(256) void aggregate_kernel(
    const int* __restrict__ eidx, const int2* __restrict__ offs2,
    const unsigned short* __restrict__ Qb, const unsigned short* __restrict__ KVb,
    float* __restrict__ out)
{
    const int n = blockIdx.x * 4 + (threadIdx.x >> 6);
    const int l = threadIdx.x & 63;
    if (n >= NNODES) return;
    const int eo = l >> 3;
    const int h  = l & 7;

    const unsigned short* qp = Qb + (size_t)n * 128 + h * 16;
    const uint4 qa = *(const uint4*)(qp);
    const uint4 qc = *(const uint4*)(qp + 8);
    float q[16];
    q[0]  = bflo(qa.x); q[1]  = bfhi(qa.x); q[2]  = bflo(qa.y); q[3]  = bfhi(qa.y);
    q[4]  = bflo(qa.z); q[5]  = bfhi(qa.z); q[6]  = bflo(qa.w); q[7]  = bfhi(qa.w);
    q[8]  = bflo(qc.x); q[9]  = bfhi(qc.x); q[10] = bflo(qc.y); q[11] = bfhi(qc.y);
    q[12] = bflo(qc.z); q[13] = bfhi(qc.z); q[14] = bflo(qc.w); q[15] = bfhi(qc.w);

    const int2 oe = offs2[n];
    const int beg = oe.x, end = oe.y;

    float acc[16];
#pragma unroll
    for (int j = 0; j < 16; ++j) acc[j] = 0.f;
    float zacc = 0.f;

    for (int i = beg; i < end; i += 16) {
        const int ei0 = i + eo;
        const int ei1 = ei0 + 8;
        const bool act0 = (ei0 < end);
        const bool act1 = (ei1 < end);
        const int s0 = eidx[act0 ? ei0 : beg];
        const int s1 = eidx[act1 ? ei1 : beg];

        const unsigned short* kp0 = KVb + (size_t)s0 * 256 + h * 16;
        const unsigned short* kp1 = KVb + (size_t)s1 * 256 + h * 16;
        const uint4 ka0 = *(const uint4*)(kp0);
        const uint4 kc0 = *(const uint4*)(kp0 + 8);
        const uint4 va0 = *(const uint4*)(kp0 + 128);
        const uint4 vc0 = *(const uint4*)(kp0 + 136);
        const uint4 ka1 = *(const uint4*)(kp1);
        const uint4 kc1 = *(const uint4*)(kp1 + 8);
        const uint4 va1 = *(const uint4*)(kp1 + 128);
        const uint4 vc1 = *(const uint4*)(kp1 + 136);

        float p0;
        p0 = fmaf(bfhi(ka0.x), q[1],  bflo(ka0.x) * q[0]);
        p0 = fmaf(bflo(ka0.y), q[2],  p0); p0 = fmaf(bfhi(ka0.y), q[3],  p0);
        p0 = fmaf(bflo(ka0.z), q[4],  p0); p0 = fmaf(bfhi(ka0.z), q[5],  p0);
        p0 = fmaf(bflo(ka0.w), q[6],  p0); p0 = fmaf(bfhi(ka0.w), q[7],  p0);
        p0 = fmaf(bflo(kc0.x), q[8],  p0); p0 = fmaf(bfhi(kc0.x), q[9],  p0);
        p0 = fmaf(bflo(kc0.y), q[10], p0); p0 = fmaf(bfhi(kc0.y), q[11], p0);
        p0 = fmaf(bflo(kc0.z), q[12], p0); p0 = fmaf(bfhi(kc0.z), q[13], p0);
        p0 = fmaf(bflo(kc0.w), q[14], p0); p0 = fmaf(bfhi(kc0.w), q[15], p0);

        float p1;
        p1 = fmaf(bfhi(ka1.x), q[1],  bflo(ka1.x) * q[0]);
        p1 = fmaf(bflo(ka1.y), q[2],  p1); p1 = fmaf(bfhi(ka1.y), q[3],  p1);
        p1 = fmaf(bflo(ka1.z), q[4],  p1); p1 = fmaf(bfhi(ka1.z), q[5],  p1);
        p1 = fmaf(bflo(ka1.w), q[6],  p1); p1 = fmaf(bfhi(ka1.w), q[7],  p1);
        p1 = fmaf(bflo(kc1.x), q[8],  p1); p1 = fmaf(bfhi(kc1.x), q[9],  p1);
        p1 = fmaf(bflo(kc1.y), q[10], p1); p1 = fmaf(bfhi(kc1.y), q[11], p1);
        p1 = fmaf(bflo(kc1.z), q[12], p1); p1 = fmaf(bfhi(kc1.z), q[13], p1);
        p1 = fmaf(bflo(kc1.w), q[14], p1); p1 = fmaf(bfhi(kc1.w), q[15], p1);

        float w0 = __expf(fminf(fmaxf(p0 * 0.25f, -5.f), 5.f));
        float w1 = __expf(fminf(fmaxf(p1 * 0.25f, -5.f), 5.f));
        w0 = act0 ? w0 : 0.f;
        w1 = act1 ? w1 : 0.f;
        zacc += w0 + w1;

        acc[0]  = fmaf(bflo(va0.x), w0, acc[0]);  acc[1]  = fmaf(bfhi(va0.x), w0, acc[1]);
        acc[2]  = fmaf(bflo(va0.y), w0, acc[2]);  acc[3]  = fmaf(bfhi(va0.y), w0, acc[3]);
        acc[4]  = fmaf(bflo(va0.z), w0, acc[4]);  acc[5]  = fmaf(bfhi(va0.z), w0, acc[5]);
        acc[6]  = fmaf(bflo(va0.w), w0, acc[6]);  acc[7]  = fmaf(bfhi(va0.w), w0, acc[7]);
        acc[8]  = fmaf(bflo(vc0.x), w0, acc[8]);  acc[9]  = fmaf(bfhi(vc0.x), w0, acc[9]);
        acc[10] = fmaf(bflo(vc0.y), w0, acc[10]); acc[11] = fmaf(bfhi(vc0.y), w0, acc[11]);
        acc[12] = fmaf(bflo(vc0.z), w0, acc[12]); acc[13] = fmaf(bfhi(vc0.z), w0, acc[13]);
        acc[14] = fmaf(bflo(vc0.w), w0, acc[14]); acc[15] = fmaf(bfhi(vc0.w), w0, acc[15]);

        acc[0]  = fmaf(bflo(va1.x), w1, acc[0]);  acc[1]  = fmaf(bfhi(va1.x), w1, acc[1]);
        acc[2]  = fmaf(bflo(va1.y), w1, acc[2]);  acc[3]  = fmaf(bfhi(va1.y), w1, acc[3]);
        acc[4]  = fmaf(bflo(va1.z), w1, acc[4]);  acc[5]  = fmaf(bfhi(va1.z), w1, acc[5]);
        acc[6]  = fmaf(bflo(va1.w), w1, acc[6]);  acc[7]  = fmaf(bfhi(va1.w), w1, acc[7]);
        acc[8]  = fmaf(bflo(vc1.x), w1, acc[8]);  acc[9]  = fmaf(bfhi(vc1.x), w1, acc[9]);
        acc[10] = fmaf(bflo(vc1.y), w1, acc[10]); acc[11] = fmaf(bfhi(vc1.y), w1, acc[11]);
        acc[12] = fmaf(bflo(vc1.z), w1, acc[12]); acc[13] = fmaf(bfhi(vc1.z), w1, acc[13]);
        acc[14] = fmaf(bflo(vc1.w), w1, acc[14]); acc[15] = fmaf(bfhi(vc1.w), w1, acc[15]);
    }

#pragma unroll
    for (int st = 8; st < 64; st <<= 1) {
        zacc += __shfl_xor(zacc, st);
#pragma unroll
        for (int j = 0; j < 16; ++j) acc[j] += __shfl_xor(acc[j], st);
    }

    if (eo == 0) {
        const float inv = 1.0f / zacc;
        float* op = out + (size_t)n * 128 + h * 16;
        *(float4*)(op)      = make_float4(acc[0]*inv,  acc[1]*inv,  acc[2]*inv,  acc[3]*inv);
        *(float4*)(op + 4)  = make_float4(acc[4]*inv,  acc[5]*inv,  acc[6]*inv,  acc[7]*inv);
        *(float4*)(op + 8)  = make_float4(acc[8]*inv,  acc[9]*inv,  acc[10]*inv, acc[11]*inv);
        *(float4*)(op + 12) = make_float4(acc[12]*inv, acc[13]*inv, acc[14]*inv, acc[15]*inv);
    }
}

extern "C" void kernel_launch(void* const* d_in, const int* in_sizes, int n_in,
                              void* d_out, int out_size, void* d_ws, size_t ws_size,
                              hipStream_t stream)
{
    const float* state = (const float*)d_in[0];
    const int*   src   = (const int*)d_in[1];
    const int*   dst   = (const int*)d_in[2];
    const float* WQ    = (const float*)d_in[3];
    const float* bQ    = (const float*)d_in[4];
    const float* WK    = (const float*)d_in[5];
    const float* bK    = (const float*)d_in[6];
    const float* WV    = (const float*)d_in[7];
    const float* bV    = (const float*)d_in[8];
    float* out = (float*)d_out;

    unsigned short* Qb  = (unsigned short*)d_ws;                 // 12.8 MB
    unsigned short* KVb = Qb + (size_t)NNODES * 128;             // 25.6 MB
    unsigned short* WT  = KVb + (size_t)NNODES * 256;            // 96 KB
    int* dbuf = (int*)(WT + 3 * 16384);                          // 8.8 MB
    int* sbuf = dbuf + (size_t)NB2 * BCAP2;                      // 8.8 MB
    int* eidx = sbuf + (size_t)NB2 * BCAP2;                      // 8.8 MB
    int* gcur = eidx + (size_t)NB2 * BCAP2;                      // 1024 ints
    int2* offs2 = (int2*)(gcur + 1024);                          // 50048 int2

    cast_wt<<<3 * 128, 128, 0, stream>>>(WQ, WK, WV, WT, gcur);
    proj_mfma<<<(NNODES + 63) / 64, 256, 0, stream>>>(state, WT, bQ, bK, bV, Qb, KVb);

    bucket_pass1<<<(NEDGES + 2047) / 2048, 256, 0, stream>>>(src, dst, gcur, dbuf, sbuf);
    bucket_pass2<<<NB2, 256, 0, stream>>>(dbuf, sbuf, gcur, eidx, offs2);

    aggregate_kernel<<<(NNODES + 3) / 4, 256, 0, stream>>>(eidx, offs2, Qb, KVb, out);
}

// Round 10
// 305.262 us; speedup vs baseline: 5.4887x; 1.1029x over previous
//
#include <hip/hip_runtime.h>

#define NNODES 50000
#define NEDGES 1600000
#define NB 196        // buckets = dst>>8 (256 nodes each)
#define BCAP 10240    // edges per bucket cap (mean 8163, +20 sigma)

typedef __attribute__((ext_vector_type(8))) short short8;   // 8 x bf16
typedef __attribute__((ext_vector_type(4))) float fp32x4;   // MFMA C/D frag

__device__ __forceinline__ unsigned short f2bf(float f) {   // RNE fp32 -> bf16
    unsigned int u = __float_as_uint(f);
    u += 0x7fffu + ((u >> 16) & 1u);
    return (unsigned short)(u >> 16);
}
__device__ __forceinline__ float bflo(unsigned int p) { return __uint_as_float(p << 16); }
__device__ __forceinline__ float bfhi(unsigned int p) { return __uint_as_float(p & 0xffff0000u); }

// ---------------------------------------------------------------------------
// Cast + transpose W (128x128 fp32, k-major) -> WT bf16 (n-major).
// Blocks 0..1 also zero gcur[256].
// ---------------------------------------------------------------------------
__global__ __launch_bounds__(128) void cast_wt(
    const float* __restrict__ WQ, const float* __restrict__ WK,
    const float* __restrict__ WV, unsigned short* __restrict__ WT,
    int* __restrict__ gcur)
{
    if (blockIdx.x < 2) gcur[blockIdx.x * 128 + threadIdx.x] = 0;
    const int w = blockIdx.x >> 7;
    const int n = blockIdx.x & 127;
    const int k = threadIdx.x;
    const float* W = (w == 0) ? WQ : ((w == 1) ? WK : WV);
    WT[w * 16384 + n * 128 + k] = f2bf(W[k * 128 + n]);
}

// ---------------------------------------------------------------------------
// QKV projection v2: blockIdx.y = which W. Per wave: B-frags for one n-tile
// live in registers while sweeping 2 row-tiles -> 64 MFMA per 48 global
// loads (round-9 version was 1:1 load:MFMA, L1-latency-bound). Block covers
// 128 rows (4 waves x 2 row-tiles x 16). Epilogue unchanged (LDS transpose).
// ---------------------------------------------------------------------------
__global__ __launch_bounds__(256) void proj_mfma(
    const float* __restrict__ state, const unsigned short* __restrict__ WT,
    const float* __restrict__ bQ, const float* __restrict__ bK,
    const float* __restrict__ bV,
    unsigned short* __restrict__ Qb, unsigned short* __restrict__ KVb)
{
    __shared__ float lbuf[4][16 * 132];

    const int w    = blockIdx.y;
    const int tid  = threadIdx.x;
    const int wv   = tid >> 6;
    const int lane = tid & 63;
    const int lm   = lane & 15;
    const int quad = lane >> 4;
    const int kq   = quad * 8;
    const unsigned short* Wp = WT + w * 16384;

    // A fragments for 2 row-tiles x 4 k-chunks (in-register fp32->bf16 cast)
    short8 a[2][4];
    int mrow[2];
#pragma unroll
    for (int rt = 0; rt < 2; ++rt) {
        const int m = blockIdx.x * 128 + rt * 64 + wv * 16 + lm;
        mrow[rt] = m;
#pragma unroll
        for (int kb = 0; kb < 4; ++kb) {
            short8 av = (short8){0,0,0,0,0,0,0,0};
            if (m < NNODES) {
                const float4 f0 = *(const float4*)(state + (size_t)m * 128 + kb * 32 + kq);
                const float4 f1 = *(const float4*)(state + (size_t)m * 128 + kb * 32 + kq + 4);
                av[0] = (short)f2bf(f0.x); av[1] = (short)f2bf(f0.y);
                av[2] = (short)f2bf(f0.z); av[3] = (short)f2bf(f0.w);
                av[4] = (short)f2bf(f1.x); av[5] = (short)f2bf(f1.y);
                av[6] = (short)f2bf(f1.z); av[7] = (short)f2bf(f1.w);
            }
            a[rt][kb] = av;
        }
    }

    fp32x4 acc[2][8];
#pragma unroll
    for (int rt = 0; rt < 2; ++rt)
#pragma unroll
        for (int t = 0; t < 8; ++t)
            acc[rt][t] = (fp32x4){0.f, 0.f, 0.f, 0.f};

#pragma unroll
    for (int t = 0; t < 8; ++t) {
        short8 b[4];
#pragma unroll
        for (int kb = 0; kb < 4; ++kb)
            b[kb] = *(const short8*)(Wp + (t * 16 + lm) * 128 + kb * 32 + kq);
#pragma unroll
        for (int rt = 0; rt < 2; ++rt)
#pragma unroll
            for (int kb = 0; kb < 4; ++kb)
                acc[rt][t] = __builtin_amdgcn_mfma_f32_16x16x32_bf16(
                    a[rt][kb], b[kb], acc[rt][t], 0, 0, 0);
    }

    // epilogue: per row-tile, bias add -> per-wave LDS transpose -> stores
    const float* bp = (w == 0) ? bQ : ((w == 1) ? bK : bV);
    const int rrow = lane >> 2;
    const int rcol = (lane & 3) * 32;
    float* L = &lbuf[wv][0];
#pragma unroll
    for (int rt = 0; rt < 2; ++rt) {
#pragma unroll
        for (int t = 0; t < 8; ++t) {
            const float bb = bp[t * 16 + lm];
#pragma unroll
            for (int r = 0; r < 4; ++r)
                L[(quad * 4 + r) * 132 + t * 16 + lm] = acc[rt][t][r] + bb;
        }
        __syncthreads();   // cheap; also orders the per-wave LDS reuse below
        const int grow = blockIdx.x * 128 + rt * 64 + wv * 16 + rrow;
        if (grow < NNODES) {
            unsigned short* gp;
            if (w == 0)      gp = Qb  + (size_t)grow * 128 + rcol;
            else if (w == 1) gp = KVb + (size_t)grow * 256 + rcol;
            else             gp = KVb + (size_t)grow * 256 + 128 + rcol;
#pragma unroll
            for (int c = 0; c < 4; ++c) {
                const float* lp = &L[rrow * 132 + rcol + c * 8];
                const float4 x0 = *(const float4*)(lp);
                const float4 x1 = *(const float4*)(lp + 4);
                short8 r;
                r[0] = (short)f2bf(x0.x); r[1] = (short)f2bf(x0.y);
                r[2] = (short)f2bf(x0.z); r[3] = (short)f2bf(x0.w);
                r[4] = (short)f2bf(x1.x); r[5] = (short)f2bf(x1.y);
                r[6] = (short)f2bf(x1.z); r[7] = (short)f2bf(x1.w);
                *(short8*)(gp + c * 8) = r;
            }
        }
        __syncthreads();
    }
}

// ---------------------------------------------------------------------------
// Pass 1: bin edges by dst>>8 into 196 buckets. 2048 edges/block. Edges
// packed (dst<<16)|src into ONE uint (both < 2^16) -> half the staging LDS
// and half the global write of the round-9 SoA version. Single-wave shfl
// scan replaces the 16-round barrier ladder.
// ---------------------------------------------------------------------------
__global__ __launch_bounds__(256) void bucket_pass1(
    const int* __restrict__ src, const int* __restrict__ dst,
    int* __restrict__ gcur, unsigned int* __restrict__ ebuf)
{
    __shared__ int hist[256];
    __shared__ int lofs[256];
    __shared__ int gbase[256];
    __shared__ int stot;
    __shared__ unsigned int stage[2048];

    const int t = threadIdx.x;
    hist[t] = 0;
    __syncthreads();

    const long long e0 = (long long)blockIdx.x * 2048 + t * 8;
    const bool valid = (e0 < NEDGES);
    int4 sA, sB, dA, dB;
    int b[8], r[8];
    if (valid) {
        sA = *(const int4*)(src + e0);  sB = *(const int4*)(src + e0 + 4);
        dA = *(const int4*)(dst + e0);  dB = *(const int4*)(dst + e0 + 4);
        const int dd[8] = {dA.x, dA.y, dA.z, dA.w, dB.x, dB.y, dB.z, dB.w};
#pragma unroll
        for (int j = 0; j < 8; ++j) {
            b[j] = dd[j] >> 8;
            r[j] = atomicAdd(&hist[b[j]], 1);
        }
    }
    __syncthreads();

    if (t < 64) {   // wave 0: scan 256 bins, 4 per lane
        const int h0 = hist[4 * t], h1 = hist[4 * t + 1],
                  h2 = hist[4 * t + 2], h3 = hist[4 * t + 3];
        const int hs = h0 + h1 + h2 + h3;
        int s = hs;
#pragma unroll
        for (int off = 1; off < 64; off <<= 1) {
            const int y = __shfl_up(s, off);
            if (t >= off) s += y;
        }
        int run = s - hs;   // exclusive
        lofs[4 * t] = run;
        if (h0 > 0) gbase[4 * t] = atomicAdd(&gcur[4 * t], h0);
        run += h0; lofs[4 * t + 1] = run;
        if (h1 > 0) gbase[4 * t + 1] = atomicAdd(&gcur[4 * t + 1], h1);
        run += h1; lofs[4 * t + 2] = run;
        if (h2 > 0) gbase[4 * t + 2] = atomicAdd(&gcur[4 * t + 2], h2);
        run += h2; lofs[4 * t + 3] = run;
        if (h3 > 0) gbase[4 * t + 3] = atomicAdd(&gcur[4 * t + 3], h3);
        if (t == 63) stot = s;
    }
    __syncthreads();

    if (valid) {
        const int dd[8] = {dA.x, dA.y, dA.z, dA.w, dB.x, dB.y, dB.z, dB.w};
        const int ss[8] = {sA.x, sA.y, sA.z, sA.w, sB.x, sB.y, sB.z, sB.w};
#pragma unroll
        for (int j = 0; j < 8; ++j)
            stage[lofs[b[j]] + r[j]] = ((unsigned int)dd[j] << 16) | (unsigned int)ss[j];
    }
    __syncthreads();

    const int tot = stot;
#pragma unroll
    for (int j = 0; j < 8; ++j) {
        const int slot = t + 256 * j;
        if (slot < tot) {
            const unsigned int e = stage[slot];
            const int bb = (int)(e >> 24);            // dst>>8
            const int loc = gbase[bb] + (slot - lofs[bb]);
            if (loc < BCAP) ebuf[bb * BCAP + loc] = e;
        }
    }
}

// ---------------------------------------------------------------------------
// Pass 2: one 512-thread block per bucket. 256-bin LDS hist, single-wave
// shfl scan -> offs2 (bucket-strided CSR), in-LDS grouping, int4 eidx write.
// ---------------------------------------------------------------------------
__global__ __launch_bounds__(512) void bucket_pass2(
    const unsigned int* __restrict__ ebuf, const int* __restrict__ gcur,
    int* __restrict__ eidx, int2* __restrict__ offs2)
{
    __shared__ int hist[256];
    __shared__ int cur[256];
    __shared__ int srcbuf[BCAP];   // 40 KB

    const int b = blockIdx.x;
    const int t = threadIdx.x;
    int cnt = gcur[b];
    if (cnt > BCAP) cnt = BCAP;
    const int base = b * BCAP;

    if (t < 256) hist[t] = 0;
    __syncthreads();

    for (int i = t; i < cnt; i += 512)
        atomicAdd(&hist[(ebuf[base + i] >> 16) & 255], 1);
    __syncthreads();

    if (t < 64) {   // wave 0: scan 256 bins, 4 per lane
        const int h0 = hist[4 * t], h1 = hist[4 * t + 1],
                  h2 = hist[4 * t + 2], h3 = hist[4 * t + 3];
        const int hs = h0 + h1 + h2 + h3;
        int s = hs;
#pragma unroll
        for (int off = 1; off < 64; off <<= 1) {
            const int y = __shfl_up(s, off);
            if (t >= off) s += y;
        }
        int run = s - hs;   // exclusive
        const int hh[4] = {h0, h1, h2, h3};
#pragma unroll
        for (int j = 0; j < 4; ++j) {
            cur[4 * t + j] = run;
            const int n = b * 256 + 4 * t + j;
            if (n < NNODES) {
                int2 oe; oe.x = base + run; oe.y = base + run + hh[j];
                offs2[n] = oe;
            }
            run += hh[j];
        }
    }
    __syncthreads();

    for (int i = t; i < cnt; i += 512) {
        const unsigned int e = ebuf[base + i];
        const int p = atomicAdd(&cur[(e >> 16) & 255], 1);
        srcbuf[p] = (int)(e & 0xffffu);
    }
    __syncthreads();

    for (int i = 4 * t; i + 3 < cnt; i += 2048)
        *(int4*)(eidx + base + i) = *(const int4*)(&srcbuf[i]);
    const int tb = cnt & ~3;
    if (t < (cnt & 3)) eidx[base + tb + t] = srcbuf[tb + t];
}

// ---------------------------------------------------------------------------
// Aggregation (round-6/9 proven, ~103 us): one wave per dst node; lane =
// (edge-slot, head); 16 edges/iter of independent dwordx4 gathers; register
// accumulation; one cross-lane reduce per node.
// ---------------------------------------------------------------------------
__global__ __launch_bounds__(256) void aggregate_kernel(
    const int* __restrict__ eidx, const int2* __restrict__ offs2,
    const unsigned short* __restrict__ Qb, const unsigned short* __restrict__ KVb,
    float* __restrict__ out)
{
    const int n = blockIdx.x * 4 + (threadIdx.x >> 6);
    const int l = threadIdx.x & 63;
    if (n >= NNODES) return;
    const int eo = l >> 3;
    const int h  = l & 7;

    const unsigned short* qp = Qb + (size_t)n * 128 + h * 16;
    const uint4 qa = *(const uint4*)(qp);
    const uint4 qc = *(const uint4*)(qp + 8);
    float q[16];
    q[0]  = bflo(qa.x); q[1]  = bfhi(qa.x); q[2]  = bflo(qa.y); q[3]  = bfhi(qa.y);
    q[4]  = bflo(qa.z); q[5]  = bfhi(qa.z); q[6]  = bflo(qa.w); q[7]  = bfhi(qa.w);
    q[8]  = bflo(qc.x); q[9]  = bfhi(qc.x); q[10] = bflo(qc.y); q[11] = bfhi(qc.y);
    q[12] = bflo(qc.z); q[13] = bfhi(qc.z); q[14] = bflo(qc.w); q[15] = bfhi(qc.w);

    const int2 oe = offs2[n];
    const int beg = oe.x, end = oe.y;

    float acc[16];
#pragma unroll
    for (int j = 0; j < 16; ++j) acc[j] = 0.f;
    float zacc = 0.f;

    for (int i = beg; i < end; i += 16) {
        const int ei0 = i + eo;
        const int ei1 = ei0 + 8;
        const bool act0 = (ei0 < end);
        const bool act1 = (ei1 < end);
        const int s0 = eidx[act0 ? ei0 : beg];
        const int s1 = eidx[act1 ? ei1 : beg];

        const unsigned short* kp0 = KVb + (size_t)s0 * 256 + h * 16;
        const unsigned short* kp1 = KVb + (size_t)s1 * 256 + h * 16;
        const uint4 ka0 = *(const uint4*)(kp0);
        const uint4 kc0 = *(const uint4*)(kp0 + 8);
        const uint4 va0 = *(const uint4*)(kp0 + 128);
        const uint4 vc0 = *(const uint4*)(kp0 + 136);
        const uint4 ka1 = *(const uint4*)(kp1);
        const uint4 kc1 = *(const uint4*)(kp1 + 8);
        const uint4 va1 = *(const uint4*)(kp1 + 128);
        const uint4 vc1 = *(const uint4*)(kp1 + 136);

        float p0;
        p0 = fmaf(bfhi(ka0.x), q[1],  bflo(ka0.x) * q[0]);
        p0 = fmaf(bflo(ka0.y), q[2],  p0); p0 = fmaf(bfhi(ka0.y), q[3],  p0);
        p0 = fmaf(bflo(ka0.z), q[4],  p0); p0 = fmaf(bfhi(ka0.z), q[5],  p0);
        p0 = fmaf(bflo(ka0.w), q[6],  p0); p0 = fmaf(bfhi(ka0.w), q[7],  p0);
        p0 = fmaf(bflo(kc0.x), q[8],  p0); p0 = fmaf(bfhi(kc0.x), q[9],  p0);
        p0 = fmaf(bflo(kc0.y), q[10], p0); p0 = fmaf(bfhi(kc0.y), q[11], p0);
        p0 = fmaf(bflo(kc0.z), q[12], p0); p0 = fmaf(bfhi(kc0.z), q[13], p0);
        p0 = fmaf(bflo(kc0.w), q[14], p0); p0 = fmaf(bfhi(kc0.w), q[15], p0);

        float p1;
        p1 = fmaf(bfhi(ka1.x), q[1],  bflo(ka1.x) * q[0]);
        p1 = fmaf(bflo(ka1.y), q[2],  p1); p1 = fmaf(bfhi(ka1.y), q[3],  p1);
        p1 = fmaf(bflo(ka1.z), q[4],  p1); p1 = fmaf(bfhi(ka1.z), q[5],  p1);
        p1 = fmaf(bflo(ka1.w), q[6],  p1); p1 = fmaf(bfhi(ka1.w), q[7],  p1);
        p1 = fmaf(bflo(kc1.x), q[8],  p1); p1 = fmaf(bfhi(kc1.x), q[9],  p1);
        p1 = fmaf(bflo(kc1.y), q[10], p1); p1 = fmaf(bfhi(kc1.y), q[11], p1);
        p1 = fmaf(bflo(kc1.z), q[12], p1); p1 = fmaf(bfhi(kc1.z), q[13], p1);
        p1 = fmaf(bflo(kc1.w), q[14], p1); p1 = fmaf(bfhi(kc1.w), q[15], p1);

        float w0 = __expf(fminf(fmaxf(p0 * 0.25f, -5.f), 5.f));
        float w1 = __expf(fminf(fmaxf(p1 * 0.25f, -5.f), 5.f));
        w0 = act0 ? w0 : 0.f;
        w1 = act1 ? w1 : 0.f;
        zacc += w0 + w1;

        acc[0]  = fmaf(bflo(va0.x), w0, acc[0]);  acc[1]  = fmaf(bfhi(va0.x), w0, acc[1]);
        acc[2]  = fmaf(bflo(va0.y), w0, acc[2]);  acc[3]  = fmaf(bfhi(va0.y), w0, acc[3]);
        acc[4]  = fmaf(bflo(va0.z), w0, acc[4]);  acc[5]  = fmaf(bfhi(va0.z), w0, acc[5]);
        acc[6]  = fmaf(bflo(va0.w), w0, acc[6]);  acc[7]  = fmaf(bfhi(va0.w), w0, acc[7]);
        acc[8]  = fmaf(bflo(vc0.x), w0, acc[8]);  acc[9]  = fmaf(bfhi(vc0.x), w0, acc[9]);
        acc[10] = fmaf(bflo(vc0.y), w0, acc[10]); acc[11] = fmaf(bfhi(vc0.y), w0, acc[11]);
        acc[12] = fmaf(bflo(vc0.z), w0, acc[12]); acc[13] = fmaf(bfhi(vc0.z), w0, acc[13]);
        acc[14] = fmaf(bflo(vc0.w), w0, acc[14]); acc[15] = fmaf(bfhi(vc0.w), w0, acc[15]);

        acc[0]  = fmaf(bflo(va1.x), w1, acc[0]);  acc[1]  = fmaf(bfhi(va1.x), w1, acc[1]);
        acc[2]  = fmaf(bflo(va1.y), w1, acc[2]);  acc[3]  = fmaf(bfhi(va1.y), w1, acc[3]);
        acc[4]  = fmaf(bflo(va1.z), w1, acc[4]);  acc[5]  = fmaf(bfhi(va1.z), w1, acc[5]);
        acc[6]  = fmaf(bflo(va1.w), w1, acc[6]);  acc[7]  = fmaf(bfhi(va1.w), w1, acc[7]);
        acc[8]  = fmaf(bflo(vc1.x), w1, acc[8]);  acc[9]  = fmaf(bfhi(vc1.x), w1, acc[9]);
        acc[10] = fmaf(bflo(vc1.y), w1, acc[10]); acc[11] = fmaf(bfhi(vc1.y), w1, acc[11]);
        acc[12] = fmaf(bflo(vc1.z), w1, acc[12]); acc[13] = fmaf(bfhi(vc1.z), w1, acc[13]);
        acc[14] = fmaf(bflo(vc1.w), w1, acc[14]); acc[15] = fmaf(bfhi(vc1.w), w1, acc[15]);
    }

#pragma unroll
    for (int st = 8; st < 64; st <<= 1) {
        zacc += __shfl_xor(zacc, st);
#pragma unroll
        for (int j = 0; j < 16; ++j) acc[j] += __shfl_xor(acc[j], st);
    }

    if (eo == 0) {
        const float inv = 1.0f / zacc;
        float* op = out + (size_t)n * 128 + h * 16;
        *(float4*)(op)      = make_float4(acc[0]*inv,  acc[1]*inv,  acc[2]*inv,  acc[3]*inv);
        *(float4*)(op + 4)  = make_float4(acc[4]*inv,  acc[5]*inv,  acc[6]*inv,  acc[7]*inv);
        *(float4*)(op + 8)  = make_float4(acc[8]*inv,  acc[9]*inv,  acc[10]*inv, acc[11]*inv);
        *(float4*)(op + 12) = make_float4(acc[12]*inv, acc[13]*inv, acc[14]*inv, acc[15]*inv);
    }
}

extern "C" void kernel_launch(void* const* d_in, const int* in_sizes, int n_in,
                              void* d_out, int out_size, void* d_ws, size_t ws_size,
                              hipStream_t stream)
{
    const float* state = (const float*)d_in[0];
    const int*   src   = (const int*)d_in[1];
    const int*   dst   = (const int*)d_in[2];
    const float* WQ    = (const float*)d_in[3];
    const float* bQ    = (const float*)d_in[4];
    const float* WK    = (const float*)d_in[5];
    const float* bK    = (const float*)d_in[6];
    const float* WV    = (const float*)d_in[7];
    const float* bV    = (const float*)d_in[8];
    float* out = (float*)d_out;

    unsigned short* Qb  = (unsigned short*)d_ws;                 // 12.8 MB
    unsigned short* KVb = Qb + (size_t)NNODES * 128;             // 25.6 MB
    unsigned short* WT  = KVb + (size_t)NNODES * 256;            // 96 KB
    unsigned int* ebuf = (unsigned int*)(WT + 3 * 16384);        // NB*BCAP*4B = 8.0 MB
    int* eidx = (int*)(ebuf + (size_t)NB * BCAP);                // 8.0 MB
    int* gcur = eidx + (size_t)NB * BCAP;                        // 256 ints
    int2* offs2 = (int2*)(gcur + 256);                           // 50176 int2

    cast_wt<<<3 * 128, 128, 0, stream>>>(WQ, WK, WV, WT, gcur);

    dim3 pgrid((NNODES + 127) / 128, 3);
    proj_mfma<<<pgrid, 256, 0, stream>>>(state, WT, bQ, bK, bV, Qb, KVb);

    bucket_pass1<<<(NEDGES + 2047) / 2048, 256, 0, stream>>>(src, dst, gcur, ebuf);
    bucket_pass2<<<NB, 512, 0, stream>>>(ebuf, gcur, eidx, offs2);

    aggregate_kernel<<<(NNODES + 3) / 4, 256, 0, stream>>>(eidx, offs2, Qb, KVb, out);
}